// Round 17
// baseline (225.179 us; speedup 1.0000x reference)
//
#include <hip/hip_runtime.h>

#define TD_ 512
#define B_  32
#define H_  512
#define TE_ 2048

typedef __attribute__((ext_vector_type(8))) short bf16x8;
typedef __attribute__((ext_vector_type(4))) short bf16x4;
typedef __attribute__((ext_vector_type(4))) float f32x4;

__device__ __forceinline__ short f2b(float f){
  union { float f; unsigned u; } v; v.f = f;
  return (short)((v.u + 0x7fffu + ((v.u >> 16) & 1u)) >> 16);  // RNE f32->bf16
}

__device__ __forceinline__ void gload16(const void* g, void* l){
  __builtin_amdgcn_global_load_lds((const __attribute__((address_space(1))) void*)g,
                                   (__attribute__((address_space(3))) void*)l,
                                   16, 0, 0);
}

#define WAVE_FENCE() do {                                   \
    asm volatile("s_waitcnt lgkmcnt(0)" ::: "memory");      \
    __builtin_amdgcn_sched_barrier(0);                      \
  } while(0)

// outputs_hidden (TD,B,H) f32 -> Abf (B,TD,H) bf16
__global__ __launch_bounds__(256) void k_cvtA(const float* __restrict__ oh,
                                              short* __restrict__ Abf){
  long base = ((long)blockIdx.x * 256 + threadIdx.x) * 4;
  int t = (int)(base >> 14);
  int rem = (int)(base & 16383);
  int b = rem >> 9, h = rem & 511;
  f32x4 v = *(const f32x4*)(oh + base);
  bf16x4 o;
  o[0]=f2b(v[0]); o[1]=f2b(v[1]); o[2]=f2b(v[2]); o[3]=f2b(v[3]);
  *(bf16x4*)(Abf + (long)b*TD_*H_ + (long)t*H_ + h) = o;
}

// encoder_out (B,H,TE) f32 -> Ebf (B,H,TE) bf16 (cast) + Ebt (B,TE,H) bf16 (transposed)
__global__ __launch_bounds__(256) void k_prep(const float* __restrict__ E,
                                              short* __restrict__ Ebf,
                                              short* __restrict__ Ebt){
  __shared__ short tile[64][72];
  int b = blockIdx.z;
  int h0 = blockIdx.y << 6, e0 = blockIdx.x << 6;
  int y = threadIdx.x >> 2;      // 0..63
  int x = threadIdx.x & 3;       // 0..3
  const float* Ein = E + ((long)b*H_ + h0 + y)*TE_ + e0 + x*16;
  short* Eo = Ebf + ((long)b*H_ + h0 + y)*TE_ + e0 + x*16;
  #pragma unroll
  for (int q=0;q<2;q++){
    f32x4 v0 = *(const f32x4*)(Ein + q*8);
    f32x4 v1 = *(const f32x4*)(Ein + q*8 + 4);
    bf16x8 o;
    o[0]=f2b(v0[0]); o[1]=f2b(v0[1]); o[2]=f2b(v0[2]); o[3]=f2b(v0[3]);
    o[4]=f2b(v1[0]); o[5]=f2b(v1[1]); o[6]=f2b(v1[2]); o[7]=f2b(v1[3]);
    *(bf16x8*)(Eo + q*8) = o;
    *(bf16x8*)(&tile[y][x*16 + q*8]) = o;
  }
  __syncthreads();
  short* Ob = Ebt + ((long)b*TE_ + e0 + y)*H_ + h0 + x*16;
  bf16x8 u0, u1;
  #pragma unroll
  for (int i2=0;i2<8;i2++) u0[i2] = tile[x*16 + i2][y];
  #pragma unroll
  for (int i2=0;i2<8;i2++) u1[i2] = tile[x*16 + 8 + i2][y];
  *(bf16x8*)(Ob) = u0;
  *(bf16x8*)(Ob + 8) = u1;
}

// GEMM1 + fused stream epilogue. BM=BN=256, BK=32; 512 blocks (8e x 2t x 32b).
// LDS: 2 bufs x (A 16KB + B 16KB) = 64 KB (+4KB rsLds) -> targets 2 blocks/CU.
// NOTE: r15's functionally-verified kernel; only launch_bounds differs (512,1):
// no forced VGPR cap (r15's (512,4) caused a 64-VGPR cap -> acc spill).
__global__ __launch_bounds__(512,1) void k_gemm1(
    const short* __restrict__ Abf, const short* __restrict__ Ebt,
    const float* __restrict__ S, float* __restrict__ NS,
    short* __restrict__ att, float* __restrict__ rsp){
  __shared__ __align__(16) char smem[65536];
  __shared__ float rsLds[4][256];
  int wg = blockIdx.x + 8*(blockIdx.y + 2*blockIdx.z);
  int lin = (wg & 7)*64 + (wg >> 3);        // bijective XCD swizzle, 512 wgs
  int bx = lin & 7, byy = (lin >> 3) & 1, b = lin >> 4;
  int t0 = byy << 8, e0 = bx << 8;

  int tid = threadIdx.x, lane = tid & 63, w = tid >> 6;
  int wr = w >> 2, wc = w & 3, g = lane >> 4, lr = lane & 15;

  const short* Ag = Abf + (long)b*TD_*H_ + (long)t0*H_;
  const short* Bg = Ebt + (long)b*TE_*H_ + (long)e0*H_;

#define STAGE_G1(dstbase, kk)                                                \
  { char* _dA = (dstbase); char* _dB = (dstbase) + 16384;                    \
    _Pragma("unroll")                                                        \
    for (int p=0;p<2;p++){                                                   \
      int cb = (w*2+p)*64; int c = cb + lane;                                \
      int row = c >> 2; int cs = (c & 3) ^ (row & 3);                        \
      gload16(Ag + (long)row*H_ + (kk) + cs*8, _dA + cb*16);                 \
      gload16(Bg + (long)row*H_ + (kk) + cs*8, _dB + cb*16);                 \
    } }

  const f32x4 fz = {0.f,0.f,0.f,0.f};
  f32x4 acc[8][4];
  #pragma unroll
  for (int m=0;m<8;m++)
    #pragma unroll
    for (int n=0;n<4;n++) acc[m][n] = fz;

  const int NT = H_/32;      // 16
  STAGE_G1(smem, 0);
  STAGE_G1(smem + 32768, 32);
  asm volatile("s_waitcnt vmcnt(4)" ::: "memory");
  __builtin_amdgcn_s_barrier();

  for (int t=0; t<NT; ++t){
    char* bA = smem + (t&1)*32768;
    char* bB = bA + 16384;
    bf16x8 af[8], bfr[4];
    #pragma unroll
    for (int m=0;m<8;m++){
      int r_ = wr*128 + m*16 + lr;
      af[m] = *(const bf16x8*)(bA + r_*64 + ((g*16) ^ ((r_&3)<<4)));
    }
    #pragma unroll
    for (int n=0;n<4;n++){
      int r_ = wc*64 + n*16 + lr;
      bfr[n] = *(const bf16x8*)(bB + r_*64 + ((g*16) ^ ((r_&3)<<4)));
    }
    __builtin_amdgcn_s_setprio(1);
    #pragma unroll
    for (int m=0;m<8;m++)
      #pragma unroll
      for (int n=0;n<4;n++)
        acc[m][n] = __builtin_amdgcn_mfma_f32_16x16x32_bf16(af[m], bfr[n], acc[m][n], 0,0,0);
    __builtin_amdgcn_s_setprio(0);
    __builtin_amdgcn_s_barrier();        // all waves done reading buf[t&1]
    if (t+2 < NT){
      STAGE_G1(smem + (t&1)*32768, (t+2)*32);
      asm volatile("s_waitcnt vmcnt(4)" ::: "memory");  // t+1 landed; t+2 in flight
      __builtin_amdgcn_s_barrier();
    } else if (t+1 < NT){
      asm volatile("s_waitcnt vmcnt(0)" ::: "memory");
      __builtin_amdgcn_s_barrier();
    }
  }
#undef STAGE_G1

  // free-running fused epilogue (per-wave private ep region + S prefetch)
  float* ep = (float*)(smem + (w << 12));   // 8 x 4 KB = 32 KB
  const float* Sb = S + (long)b*TD_*TE_;
  float* NSb = NS + (long)b*TD_*TE_;
  short* attb = att + (long)b*TD_*TE_;
  int elc = (lane & 15) * 4;

  f32x4 svp[4];
  #pragma unroll
  for (int j=0;j<4;j++){
    int tr = j*4 + (lane >> 4);
    long off = (long)(t0 + wr*128 + tr)*TE_ + e0 + wc*64 + elc;
    svp[j] = *(const f32x4*)(Sb + off);
  }

  #pragma unroll
  for (int m=0;m<8;m++){
    #pragma unroll
    for (int n=0;n<4;n++){
      #pragma unroll
      for (int r=0;r<4;r++){
        int tr = g*4 + r;
        ep[tr*64 + ((n*16 + lr) ^ (tr << 2))] = acc[m][n][r];
      }
    }
    WAVE_FENCE();
    f32x4 svn[4];
    if (m < 7){
      #pragma unroll
      for (int j=0;j<4;j++){
        int tr = j*4 + (lane >> 4);
        long off = (long)(t0 + wr*128 + (m+1)*16 + tr)*TE_ + e0 + wc*64 + elc;
        svn[j] = *(const f32x4*)(Sb + off);
      }
    }
    #pragma unroll
    for (int j=0;j<4;j++){
      int tr = j*4 + (lane >> 4);
      f32x4 c4 = *(const f32x4*)(ep + tr*64 + (elc ^ (tr << 2)));
      int tl = wr*128 + m*16 + tr;
      long off = (long)(t0 + tl)*TE_ + e0 + wc*64 + elc;
      f32x4 sv = svp[j];
      f32x4 ns; bf16x4 ab; float rp = 0.f;
      #pragma unroll
      for (int i=0;i<4;i++){
        float ta = __expf(c4[i]);
        ns[i] = ta + sv[i];
        float av = ta * __builtin_amdgcn_rcpf(sv[i]);
        ab[i] = f2b(av);
        rp += av;
      }
      *(f32x4*)(NSb + off) = ns;
      *(bf16x4*)(attb + off) = ab;
      rp += __shfl_xor(rp, 1);
      rp += __shfl_xor(rp, 2);
      rp += __shfl_xor(rp, 4);
      rp += __shfl_xor(rp, 8);
      if (lr == 0) rsLds[wc][tl] = rp;   // single writer per (wc,row)
    }
    if (m < 7){
      #pragma unroll
      for (int j=0;j<4;j++) svp[j] = svn[j];
    }
    WAVE_FENCE();
  }

  __syncthreads();                        // publish rsLds across waves
  if (tid < 256){
    float v = rsLds[0][tid] + rsLds[1][tid] + rsLds[2][tid] + rsLds[3][tid];
    rsp[((long)b*8 + bx)*TD_ + t0 + tid] = v;
  }
}

// ---- k_ctx: r13-exact 128x128 BK=64 4-wave pipelined GEMM ----
#define STAGE12(dstbase, Asrc, Bsrc, ld, kk)                                 \
  { char* _dA = (dstbase); char* _dB = (dstbase) + 16384;                    \
    _Pragma("unroll")                                                        \
    for (int p=0;p<4;p++){                                                   \
      int cb = (w*4+p)*64; int c = cb + lane;                                \
      int row = c >> 3; int cs = (c & 7) ^ (row & 7);                        \
      gload16((Asrc) + (long)row*(ld) + (kk) + cs*8, _dA + cb*16);           \
      gload16((Bsrc) + (long)row*(ld) + (kk) + cs*8, _dB + cb*16);           \
    } }

#define FRAGS12(bA, bB)                                                      \
    _Pragma("unroll")                                                        \
    for (int ks=0;ks<2;ks++){                                                \
      bf16x8 af[4], bfr[4];                                                  \
      _Pragma("unroll")                                                      \
      for (int m=0;m<4;m++){                                                 \
        int r_ = wr*64 + m*16 + lr;                                          \
        af[m] = *(const bf16x8*)((bA) + r_*128 + ((ks*64 + g*16) ^ ((r_&7)<<4))); \
      }                                                                      \
      _Pragma("unroll")                                                      \
      for (int n=0;n<4;n++){                                                 \
        int r_ = wc*64 + n*16 + lr;                                          \
        bfr[n] = *(const bf16x8*)((bB) + r_*128 + ((ks*64 + g*16) ^ ((r_&7)<<4))); \
      }                                                                      \
      __builtin_amdgcn_s_setprio(1);                                         \
      _Pragma("unroll")                                                      \
      for (int m=0;m<4;m++)                                                  \
        _Pragma("unroll")                                                    \
        for (int n=0;n<4;n++)                                                \
          acc[m][n] = __builtin_amdgcn_mfma_f32_16x16x32_bf16(af[m], bfr[n], acc[m][n], 0,0,0); \
      __builtin_amdgcn_s_setprio(0);                                         \
    }

__global__ __launch_bounds__(256,1) void k_ctx(
    const short* __restrict__ att, const short* __restrict__ Ebf,
    const float* __restrict__ rsp, float* __restrict__ ctx){
  __shared__ __align__(16) char smem[65536];
  __shared__ float invRs[128];
  int wg = blockIdx.x + 4*(blockIdx.y + 4*blockIdx.z);
  int lin = (wg & 7)*64 + (wg >> 3);
  int bx = lin & 3, byy = (lin >> 2) & 3, b = lin >> 4;
  int t0 = byy << 7, h0 = bx << 7;

  int tid = threadIdx.x, lane = tid & 63, w = tid >> 6;
  int wr = w >> 1, wc = w & 1, g = lane >> 4, lr = lane & 15;

  if (tid < 128){
    float s = 0.f;
    #pragma unroll
    for (int k=0;k<8;k++) s += rsp[((long)b*8 + k)*TD_ + t0 + tid];
    invRs[tid] = __builtin_amdgcn_rcpf(s);
  }

  const short* Ag = att + (long)b*TD_*TE_ + (long)t0*TE_;
  const short* Bg = Ebf + (long)b*H_*TE_ + (long)h0*TE_;

  const f32x4 fz = {0.f,0.f,0.f,0.f};
  f32x4 acc[4][4];
  #pragma unroll
  for (int m=0;m<4;m++)
    #pragma unroll
    for (int n=0;n<4;n++) acc[m][n] = fz;

  const int NT = TE_/64;     // 32
  STAGE12(smem,       Ag, Bg, TE_, 0);
  STAGE12(smem+32768, Ag, Bg, TE_, 64);
  asm volatile("s_waitcnt vmcnt(8)" ::: "memory");
  __builtin_amdgcn_s_barrier();

  for (int t=0; t<NT; ++t){
    char* bA = smem + (t&1)*32768;
    char* bB = bA + 16384;
    FRAGS12(bA, bB);
    __builtin_amdgcn_s_barrier();
    if (t+2 < NT){
      STAGE12(smem + (t&1)*32768, Ag, Bg, TE_, (t+2)*64);
      asm volatile("s_waitcnt vmcnt(8)" ::: "memory");
      __builtin_amdgcn_s_barrier();
    } else if (t+1 < NT){
      asm volatile("s_waitcnt vmcnt(0)" ::: "memory");
      __builtin_amdgcn_s_barrier();
    }
  }

  // free-running epilogue: per-wave private transpose + wave-local fences
  float* ep = (float*)(smem + (w << 12));
  int hlc = (lane & 15) * 4;
  #pragma unroll
  for (int m=0;m<4;m++){
    #pragma unroll
    for (int n=0;n<4;n++){
      #pragma unroll
      for (int r=0;r<4;r++){
        int tr = g*4 + r;
        ep[tr*64 + ((n*16 + lr) ^ (tr << 2))] = acc[m][n][r];
      }
    }
    WAVE_FENCE();
    #pragma unroll
    for (int j=0;j<4;j++){
      int tr = j*4 + (lane >> 4);
      f32x4 c4 = *(const f32x4*)(ep + tr*64 + (hlc ^ (tr << 2)));
      int tl = wr*64 + m*16 + tr;
      float inv = invRs[tl];
      c4[0]*=inv; c4[1]*=inv; c4[2]*=inv; c4[3]*=inv;
      *(f32x4*)(ctx + (long)(t0 + tl)*B_*H_ + (long)b*H_ + h0 + wc*64 + hlc) = c4;
    }
    WAVE_FENCE();
  }
}

extern "C" void kernel_launch(void* const* d_in, const int* in_sizes, int n_in,
                              void* d_out, int out_size, void* d_ws, size_t ws_size,
                              hipStream_t stream){
  const float* oh = (const float*)d_in[0];   // (TD,B,H)
  const float* E  = (const float*)d_in[1];   // (B,H,TE)
  const float* S  = (const float*)d_in[2];   // (B,TD,TE)
  float* out_ctx = (float*)d_out;                       // (TD,B,H)
  float* out_ns  = out_ctx + (long)TD_*B_*H_;           // (B,TD,TE)

  char* ws = (char*)d_ws;
  size_t offEbt = 0;
  size_t offEbf = offEbt + (size_t)B_*TE_*H_*2;   // 64 MiB
  size_t offA   = offEbf + (size_t)B_*H_*TE_*2;   // 64 MiB
  size_t offAt  = offA   + (size_t)B_*TD_*H_*2;   // 16 MiB
  size_t offRsp = offAt  + (size_t)B_*TD_*TE_*2;  // 64 MiB (att bf16)
  short* Ebt  = (short*)(ws + offEbt);
  short* Ebf  = (short*)(ws + offEbf);
  short* Abf  = (short*)(ws + offA);
  short* attw = (short*)(ws + offAt);
  float* rsp  = (float*)(ws + offRsp);            // [B][8][TD] partials: 512 KiB

  k_cvtA<<<dim3((TD_*B_*H_)/(256*4)), 256, 0, stream>>>(oh, Abf);
  k_prep<<<dim3(TE_/64, H_/64, B_), 256, 0, stream>>>(E, Ebf, Ebt);
  k_gemm1<<<dim3(TE_/256, TD_/256, B_), 512, 0, stream>>>(Abf, Ebt, S, out_ns, attw, rsp);
  k_ctx<<<dim3(H_/128, TD_/128, B_), 256, 0, stream>>>(attw, Ebf, rsp, out_ctx);
}

// Round 18
// 218.007 us; speedup vs baseline: 1.0329x; 1.0329x over previous
//
#include <hip/hip_runtime.h>

#define TD_ 512
#define B_  32
#define H_  512
#define TE_ 2048

typedef __attribute__((ext_vector_type(8))) short bf16x8;
typedef __attribute__((ext_vector_type(4))) short bf16x4;
typedef __attribute__((ext_vector_type(4))) float f32x4;

__device__ __forceinline__ short f2b(float f){
  union { float f; unsigned u; } v; v.f = f;
  return (short)((v.u + 0x7fffu + ((v.u >> 16) & 1u)) >> 16);  // RNE f32->bf16
}

__device__ __forceinline__ void gload16(const void* g, void* l){
  __builtin_amdgcn_global_load_lds((const __attribute__((address_space(1))) void*)g,
                                   (__attribute__((address_space(3))) void*)l,
                                   16, 0, 0);
}

#define WAVE_FENCE() do {                                   \
    asm volatile("s_waitcnt lgkmcnt(0)" ::: "memory");      \
    __builtin_amdgcn_sched_barrier(0);                      \
  } while(0)

// Merged prep: blockIdx.y < 8  -> E-prep tile (Ebf cast + Ebt transpose)
//              blockIdx.y >= 8 -> oh (TD,B,H) f32 -> Abf (B,TD,H) bf16 chunk
__global__ __launch_bounds__(256) void k_prep_all(
    const float* __restrict__ E, short* __restrict__ Ebf, short* __restrict__ Ebt,
    const float* __restrict__ oh, short* __restrict__ Abf){
  if (blockIdx.y < 8){
    __shared__ short tile[64][72];
    int b = blockIdx.z;
    int h0 = blockIdx.y << 6, e0 = blockIdx.x << 6;
    int y = threadIdx.x >> 2;      // 0..63
    int x = threadIdx.x & 3;       // 0..3
    const float* Ein = E + ((long)b*H_ + h0 + y)*TE_ + e0 + x*16;
    short* Eo = Ebf + ((long)b*H_ + h0 + y)*TE_ + e0 + x*16;
    #pragma unroll
    for (int q=0;q<2;q++){
      f32x4 v0 = *(const f32x4*)(Ein + q*8);
      f32x4 v1 = *(const f32x4*)(Ein + q*8 + 4);
      bf16x8 o;
      o[0]=f2b(v0[0]); o[1]=f2b(v0[1]); o[2]=f2b(v0[2]); o[3]=f2b(v0[3]);
      o[4]=f2b(v1[0]); o[5]=f2b(v1[1]); o[6]=f2b(v1[2]); o[7]=f2b(v1[3]);
      *(bf16x8*)(Eo + q*8) = o;
      *(bf16x8*)(&tile[y][x*16 + q*8]) = o;
    }
    __syncthreads();
    short* Ob = Ebt + ((long)b*TE_ + e0 + y)*H_ + h0 + x*16;
    bf16x8 u0, u1;
    #pragma unroll
    for (int i2=0;i2<8;i2++) u0[i2] = tile[x*16 + i2][y];
    #pragma unroll
    for (int i2=0;i2<8;i2++) u1[i2] = tile[x*16 + 8 + i2][y];
    *(bf16x8*)(Ob) = u0;
    *(bf16x8*)(Ob + 8) = u1;
  } else {
    int cid = ((blockIdx.y - 8)*32 + blockIdx.x)*32 + blockIdx.z;  // 0..8191
    long base = ((long)cid * 256 + threadIdx.x) * 4;
    int t = (int)(base >> 14);
    int rem = (int)(base & 16383);
    int b = rem >> 9, h = rem & 511;
    f32x4 v = *(const f32x4*)(oh + base);
    bf16x4 o;
    o[0]=f2b(v[0]); o[1]=f2b(v[1]); o[2]=f2b(v[2]); o[3]=f2b(v[3]);
    *(bf16x4*)(Abf + (long)b*TD_*H_ + (long)t*H_ + h) = o;
  }
}

// GEMM1 + fused stream epilogue (r16-exact, measured 95.9 us).
// BM=BN=256, BK=64; 512 blocks (8e x 2t x 32b); 131 KB LDS; VGPR ~128.
__global__ __launch_bounds__(512,1) void k_gemm1(
    const short* __restrict__ Abf, const short* __restrict__ Ebt,
    const float* __restrict__ S, float* __restrict__ NS,
    short* __restrict__ att, float* __restrict__ rsp){
  __shared__ __align__(16) char smem[131072];
  __shared__ float rsLds[4][256];
  int wg = blockIdx.x + 8*(blockIdx.y + 2*blockIdx.z);
  int lin = (wg & 7)*64 + (wg >> 3);        // bijective XCD swizzle, 512 wgs
  int bx = lin & 7, byy = (lin >> 3) & 1, b = lin >> 4;
  int t0 = byy << 8, e0 = bx << 8;

  int tid = threadIdx.x, lane = tid & 63, w = tid >> 6;
  int wr = w >> 2, wc = w & 3, g = lane >> 4, lr = lane & 15;

  const short* Ag = Abf + (long)b*TD_*H_ + (long)t0*H_;
  const short* Bg = Ebt + (long)b*TE_*H_ + (long)e0*H_;

#define STAGE_G1(dstbase, kk)                                                \
  { char* _dA = (dstbase); char* _dB = (dstbase) + 32768;                    \
    _Pragma("unroll")                                                        \
    for (int p=0;p<4;p++){                                                   \
      int cb = (w*4+p)*64; int c = cb + lane;                                \
      int row = c >> 3; int cs = (c & 7) ^ (row & 7);                        \
      gload16(Ag + (long)row*H_ + (kk) + cs*8, _dA + cb*16);                 \
      gload16(Bg + (long)row*H_ + (kk) + cs*8, _dB + cb*16);                 \
    } }

  const f32x4 fz = {0.f,0.f,0.f,0.f};
  f32x4 acc[8][4];
  #pragma unroll
  for (int m=0;m<8;m++)
    #pragma unroll
    for (int n=0;n<4;n++) acc[m][n] = fz;

  const int NT = H_/64;      // 8
  STAGE_G1(smem, 0);
  STAGE_G1(smem + 65536, 64);
  asm volatile("s_waitcnt vmcnt(8)" ::: "memory");
  __builtin_amdgcn_s_barrier();

  for (int t=0; t<NT; ++t){
    char* bA = smem + (t&1)*65536;
    char* bB = bA + 32768;
    #pragma unroll
    for (int ks=0; ks<2; ++ks){
      bf16x8 af[8], bfr[4];
      #pragma unroll
      for (int m=0;m<8;m++){
        int r_ = wr*128 + m*16 + lr;
        af[m] = *(const bf16x8*)(bA + r_*128 + ((ks*64 + g*16) ^ ((r_&7)<<4)));
      }
      #pragma unroll
      for (int n=0;n<4;n++){
        int r_ = wc*64 + n*16 + lr;
        bfr[n] = *(const bf16x8*)(bB + r_*128 + ((ks*64 + g*16) ^ ((r_&7)<<4)));
      }
      __builtin_amdgcn_s_setprio(1);
      #pragma unroll
      for (int m=0;m<8;m++)
        #pragma unroll
        for (int n=0;n<4;n++)
          acc[m][n] = __builtin_amdgcn_mfma_f32_16x16x32_bf16(af[m], bfr[n], acc[m][n], 0,0,0);
      __builtin_amdgcn_s_setprio(0);
    }
    __builtin_amdgcn_s_barrier();
    if (t+2 < NT){
      STAGE_G1(smem + (t&1)*65536, (t+2)*64);
      asm volatile("s_waitcnt vmcnt(8)" ::: "memory");
      __builtin_amdgcn_s_barrier();
    } else if (t+1 < NT){
      asm volatile("s_waitcnt vmcnt(0)" ::: "memory");
      __builtin_amdgcn_s_barrier();
    }
  }
#undef STAGE_G1

  // free-running fused epilogue (per-wave private ep region + S prefetch)
  float* ep = (float*)(smem + (w << 12));   // 8 x 4 KB
  const float* Sb = S + (long)b*TD_*TE_;
  float* NSb = NS + (long)b*TD_*TE_;
  short* attb = att + (long)b*TD_*TE_;
  int elc = (lane & 15) * 4;

  f32x4 svp[4];
  #pragma unroll
  for (int j=0;j<4;j++){
    int tr = j*4 + (lane >> 4);
    long off = (long)(t0 + wr*128 + tr)*TE_ + e0 + wc*64 + elc;
    svp[j] = *(const f32x4*)(Sb + off);
  }

  #pragma unroll
  for (int m=0;m<8;m++){
    #pragma unroll
    for (int n=0;n<4;n++){
      #pragma unroll
      for (int r=0;r<4;r++){
        int tr = g*4 + r;
        ep[tr*64 + ((n*16 + lr) ^ (tr << 2))] = acc[m][n][r];
      }
    }
    WAVE_FENCE();
    f32x4 svn[4];
    if (m < 7){
      #pragma unroll
      for (int j=0;j<4;j++){
        int tr = j*4 + (lane >> 4);
        long off = (long)(t0 + wr*128 + (m+1)*16 + tr)*TE_ + e0 + wc*64 + elc;
        svn[j] = *(const f32x4*)(Sb + off);
      }
    }
    #pragma unroll
    for (int j=0;j<4;j++){
      int tr = j*4 + (lane >> 4);
      f32x4 c4 = *(const f32x4*)(ep + tr*64 + (elc ^ (tr << 2)));
      int tl = wr*128 + m*16 + tr;
      long off = (long)(t0 + tl)*TE_ + e0 + wc*64 + elc;
      f32x4 sv = svp[j];
      f32x4 ns; bf16x4 ab; float rp = 0.f;
      #pragma unroll
      for (int i=0;i<4;i++){
        float ta = __expf(c4[i]);
        ns[i] = ta + sv[i];
        float av = ta * __builtin_amdgcn_rcpf(sv[i]);
        ab[i] = f2b(av);
        rp += av;
      }
      *(f32x4*)(NSb + off) = ns;
      *(bf16x4*)(attb + off) = ab;
      rp += __shfl_xor(rp, 1);
      rp += __shfl_xor(rp, 2);
      rp += __shfl_xor(rp, 4);
      rp += __shfl_xor(rp, 8);
      if (lr == 0) rsLds[wc][tl] = rp;   // single writer per (wc,row)
    }
    if (m < 7){
      #pragma unroll
      for (int j=0;j<4;j++) svp[j] = svn[j];
    }
    WAVE_FENCE();
  }

  __syncthreads();                        // publish rsLds across waves
  if (tid < 256){
    float v = rsLds[0][tid] + rsLds[1][tid] + rsLds[2][tid] + rsLds[3][tid];
    rsp[((long)b*8 + bx)*TD_ + t0 + tid] = v;
  }
}

// ---- k_ctx: r13-exact 128x128 BK=64 4-wave pipelined GEMM ----
#define STAGE12(dstbase, Asrc, Bsrc, ld, kk)                                 \
  { char* _dA = (dstbase); char* _dB = (dstbase) + 16384;                    \
    _Pragma("unroll")                                                        \
    for (int p=0;p<4;p++){                                                   \
      int cb = (w*4+p)*64; int c = cb + lane;                                \
      int row = c >> 3; int cs = (c & 7) ^ (row & 7);                        \
      gload16((Asrc) + (long)row*(ld) + (kk) + cs*8, _dA + cb*16);           \
      gload16((Bsrc) + (long)row*(ld) + (kk) + cs*8, _dB + cb*16);           \
    } }

#define FRAGS12(bA, bB)                                                      \
    _Pragma("unroll")                                                        \
    for (int ks=0;ks<2;ks++){                                                \
      bf16x8 af[4], bfr[4];                                                  \
      _Pragma("unroll")                                                      \
      for (int m=0;m<4;m++){                                                 \
        int r_ = wr*64 + m*16 + lr;                                          \
        af[m] = *(const bf16x8*)((bA) + r_*128 + ((ks*64 + g*16) ^ ((r_&7)<<4))); \
      }                                                                      \
      _Pragma("unroll")                                                      \
      for (int n=0;n<4;n++){                                                 \
        int r_ = wc*64 + n*16 + lr;                                          \
        bfr[n] = *(const bf16x8*)((bB) + r_*128 + ((ks*64 + g*16) ^ ((r_&7)<<4))); \
      }                                                                      \
      __builtin_amdgcn_s_setprio(1);                                         \
      _Pragma("unroll")                                                      \
      for (int m=0;m<4;m++)                                                  \
        _Pragma("unroll")                                                    \
        for (int n=0;n<4;n++)                                                \
          acc[m][n] = __builtin_amdgcn_mfma_f32_16x16x32_bf16(af[m], bfr[n], acc[m][n], 0,0,0); \
      __builtin_amdgcn_s_setprio(0);                                         \
    }

__global__ __launch_bounds__(256,1) void k_ctx(
    const short* __restrict__ att, const short* __restrict__ Ebf,
    const float* __restrict__ rsp, float* __restrict__ ctx){
  __shared__ __align__(16) char smem[65536];
  __shared__ float invRs[128];
  int wg = blockIdx.x + 4*(blockIdx.y + 4*blockIdx.z);
  int lin = (wg & 7)*64 + (wg >> 3);
  int bx = lin & 3, byy = (lin >> 2) & 3, b = lin >> 4;
  int t0 = byy << 7, h0 = bx << 7;

  int tid = threadIdx.x, lane = tid & 63, w = tid >> 6;
  int wr = w >> 1, wc = w & 1, g = lane >> 4, lr = lane & 15;

  if (tid < 128){
    float s = 0.f;
    #pragma unroll
    for (int k=0;k<8;k++) s += rsp[((long)b*8 + k)*TD_ + t0 + tid];
    invRs[tid] = __builtin_amdgcn_rcpf(s);
  }

  const short* Ag = att + (long)b*TD_*TE_ + (long)t0*TE_;
  const short* Bg = Ebf + (long)b*H_*TE_ + (long)h0*TE_;

  const f32x4 fz = {0.f,0.f,0.f,0.f};
  f32x4 acc[4][4];
  #pragma unroll
  for (int m=0;m<4;m++)
    #pragma unroll
    for (int n=0;n<4;n++) acc[m][n] = fz;

  const int NT = TE_/64;     // 32
  STAGE12(smem,       Ag, Bg, TE_, 0);
  STAGE12(smem+32768, Ag, Bg, TE_, 64);
  asm volatile("s_waitcnt vmcnt(8)" ::: "memory");
  __builtin_amdgcn_s_barrier();

  for (int t=0; t<NT; ++t){
    char* bA = smem + (t&1)*32768;
    char* bB = bA + 16384;
    FRAGS12(bA, bB);
    __builtin_amdgcn_s_barrier();
    if (t+2 < NT){
      STAGE12(smem + (t&1)*32768, Ag, Bg, TE_, (t+2)*64);
      asm volatile("s_waitcnt vmcnt(8)" ::: "memory");
      __builtin_amdgcn_s_barrier();
    } else if (t+1 < NT){
      asm volatile("s_waitcnt vmcnt(0)" ::: "memory");
      __builtin_amdgcn_s_barrier();
    }
  }

  // free-running epilogue: per-wave private transpose + wave-local fences
  float* ep = (float*)(smem + (w << 12));
  int hlc = (lane & 15) * 4;
  #pragma unroll
  for (int m=0;m<4;m++){
    #pragma unroll
    for (int n=0;n<4;n++){
      #pragma unroll
      for (int r=0;r<4;r++){
        int tr = g*4 + r;
        ep[tr*64 + ((n*16 + lr) ^ (tr << 2))] = acc[m][n][r];
      }
    }
    WAVE_FENCE();
    #pragma unroll
    for (int j=0;j<4;j++){
      int tr = j*4 + (lane >> 4);
      f32x4 c4 = *(const f32x4*)(ep + tr*64 + (hlc ^ (tr << 2)));
      int tl = wr*64 + m*16 + tr;
      float inv = invRs[tl];
      c4[0]*=inv; c4[1]*=inv; c4[2]*=inv; c4[3]*=inv;
      *(f32x4*)(ctx + (long)(t0 + tl)*B_*H_ + (long)b*H_ + h0 + wc*64 + hlc) = c4;
    }
    WAVE_FENCE();
  }
}

extern "C" void kernel_launch(void* const* d_in, const int* in_sizes, int n_in,
                              void* d_out, int out_size, void* d_ws, size_t ws_size,
                              hipStream_t stream){
  const float* oh = (const float*)d_in[0];   // (TD,B,H)
  const float* E  = (const float*)d_in[1];   // (B,H,TE)
  const float* S  = (const float*)d_in[2];   // (B,TD,TE)
  float* out_ctx = (float*)d_out;                       // (TD,B,H)
  float* out_ns  = out_ctx + (long)TD_*B_*H_;           // (B,TD,TE)

  char* ws = (char*)d_ws;
  size_t offEbt = 0;
  size_t offEbf = offEbt + (size_t)B_*TE_*H_*2;   // 64 MiB
  size_t offA   = offEbf + (size_t)B_*H_*TE_*2;   // 64 MiB
  size_t offAt  = offA   + (size_t)B_*TD_*H_*2;   // 16 MiB
  size_t offRsp = offAt  + (size_t)B_*TD_*TE_*2;  // 64 MiB (att bf16)
  short* Ebt  = (short*)(ws + offEbt);
  short* Ebf  = (short*)(ws + offEbf);
  short* Abf  = (short*)(ws + offA);
  short* attw = (short*)(ws + offAt);
  float* rsp  = (float*)(ws + offRsp);            // [B][8][TD] partials: 512 KiB

  k_prep_all<<<dim3(32, 16, 32), 256, 0, stream>>>(E, Ebf, Ebt, oh, Abf);
  k_gemm1<<<dim3(TE_/256, TD_/256, B_), 512, 0, stream>>>(Abf, Ebt, S, out_ns, attw, rsp);
  k_ctx<<<dim3(H_/128, TD_/128, B_), 256, 0, stream>>>(attw, Ebf, rsp, out_ctx);
}

// Round 19
// 215.633 us; speedup vs baseline: 1.0443x; 1.0110x over previous
//
#include <hip/hip_runtime.h>

#define TD_ 512
#define B_  32
#define H_  512
#define TE_ 2048

typedef __attribute__((ext_vector_type(8))) short bf16x8;
typedef __attribute__((ext_vector_type(4))) short bf16x4;
typedef __attribute__((ext_vector_type(4))) float f32x4;

__device__ __forceinline__ short f2b(float f){
  union { float f; unsigned u; } v; v.f = f;
  return (short)((v.u + 0x7fffu + ((v.u >> 16) & 1u)) >> 16);  // RNE f32->bf16
}

__device__ __forceinline__ void gload16(const void* g, void* l){
  __builtin_amdgcn_global_load_lds((const __attribute__((address_space(1))) void*)g,
                                   (__attribute__((address_space(3))) void*)l,
                                   16, 0, 0);
}

#define WAVE_FENCE() do {                                   \
    asm volatile("s_waitcnt lgkmcnt(0)" ::: "memory");      \
    __builtin_amdgcn_sched_barrier(0);                      \
  } while(0)

// Merged prep: blockIdx.y < 8  -> E-prep tile (Ebf cast + Ebt transpose)
//              blockIdx.y >= 8 -> oh (TD,B,H) f32 -> Abf (B,TD,H) bf16 chunk
__global__ __launch_bounds__(256) void k_prep_all(
    const float* __restrict__ E, short* __restrict__ Ebf, short* __restrict__ Ebt,
    const float* __restrict__ oh, short* __restrict__ Abf){
  if (blockIdx.y < 8){
    __shared__ short tile[64][72];
    int b = blockIdx.z;
    int h0 = blockIdx.y << 6, e0 = blockIdx.x << 6;
    int y = threadIdx.x >> 2;      // 0..63
    int x = threadIdx.x & 3;       // 0..3
    const float* Ein = E + ((long)b*H_ + h0 + y)*TE_ + e0 + x*16;
    short* Eo = Ebf + ((long)b*H_ + h0 + y)*TE_ + e0 + x*16;
    #pragma unroll
    for (int q=0;q<2;q++){
      f32x4 v0 = *(const f32x4*)(Ein + q*8);
      f32x4 v1 = *(const f32x4*)(Ein + q*8 + 4);
      bf16x8 o;
      o[0]=f2b(v0[0]); o[1]=f2b(v0[1]); o[2]=f2b(v0[2]); o[3]=f2b(v0[3]);
      o[4]=f2b(v1[0]); o[5]=f2b(v1[1]); o[6]=f2b(v1[2]); o[7]=f2b(v1[3]);
      *(bf16x8*)(Eo + q*8) = o;
      *(bf16x8*)(&tile[y][x*16 + q*8]) = o;
    }
    __syncthreads();
    short* Ob = Ebt + ((long)b*TE_ + e0 + y)*H_ + h0 + x*16;
    bf16x8 u0, u1;
    #pragma unroll
    for (int i2=0;i2<8;i2++) u0[i2] = tile[x*16 + i2][y];
    #pragma unroll
    for (int i2=0;i2<8;i2++) u1[i2] = tile[x*16 + 8 + i2][y];
    *(bf16x8*)(Ob) = u0;
    *(bf16x8*)(Ob + 8) = u1;
  } else {
    int cid = ((blockIdx.y - 8)*32 + blockIdx.x)*32 + blockIdx.z;  // 0..8191
    long base = ((long)cid * 256 + threadIdx.x) * 4;
    int t = (int)(base >> 14);
    int rem = (int)(base & 16383);
    int b = rem >> 9, h = rem & 511;
    f32x4 v = *(const f32x4*)(oh + base);
    bf16x4 o;
    o[0]=f2b(v[0]); o[1]=f2b(v[1]); o[2]=f2b(v[2]); o[3]=f2b(v[3]);
    *(bf16x4*)(Abf + (long)b*TD_*H_ + (long)t*H_ + h) = o;
  }
}

// GEMM1 + fused stream epilogue. BM=BN=256, BK=64; 512 blocks (8e x 2t x 32b).
// Epilogue uses ping-pong per-wave ep buffers: write(m+1) overlaps compute(m).
__global__ __launch_bounds__(512,1) void k_gemm1(
    const short* __restrict__ Abf, const short* __restrict__ Ebt,
    const float* __restrict__ S, float* __restrict__ NS,
    short* __restrict__ att, float* __restrict__ rsp){
  __shared__ __align__(16) char smem[131072];
  __shared__ float rsLds[4][256];
  int wg = blockIdx.x + 8*(blockIdx.y + 2*blockIdx.z);
  int lin = (wg & 7)*64 + (wg >> 3);        // bijective XCD swizzle, 512 wgs
  int bx = lin & 7, byy = (lin >> 3) & 1, b = lin >> 4;
  int t0 = byy << 8, e0 = bx << 8;

  int tid = threadIdx.x, lane = tid & 63, w = tid >> 6;
  int wr = w >> 2, wc = w & 3, g = lane >> 4, lr = lane & 15;

  const short* Ag = Abf + (long)b*TD_*H_ + (long)t0*H_;
  const short* Bg = Ebt + (long)b*TE_*H_ + (long)e0*H_;

#define STAGE_G1(dstbase, kk)                                                \
  { char* _dA = (dstbase); char* _dB = (dstbase) + 32768;                    \
    _Pragma("unroll")                                                        \
    for (int p=0;p<4;p++){                                                   \
      int cb = (w*4+p)*64; int c = cb + lane;                                \
      int row = c >> 3; int cs = (c & 7) ^ (row & 7);                        \
      gload16(Ag + (long)row*H_ + (kk) + cs*8, _dA + cb*16);                 \
      gload16(Bg + (long)row*H_ + (kk) + cs*8, _dB + cb*16);                 \
    } }

  const f32x4 fz = {0.f,0.f,0.f,0.f};
  f32x4 acc[8][4];
  #pragma unroll
  for (int m=0;m<8;m++)
    #pragma unroll
    for (int n=0;n<4;n++) acc[m][n] = fz;

  const int NT = H_/64;      // 8
  STAGE_G1(smem, 0);
  STAGE_G1(smem + 65536, 64);
  asm volatile("s_waitcnt vmcnt(8)" ::: "memory");
  __builtin_amdgcn_s_barrier();

  for (int t=0; t<NT; ++t){
    char* bA = smem + (t&1)*65536;
    char* bB = bA + 32768;
    #pragma unroll
    for (int ks=0; ks<2; ++ks){
      bf16x8 af[8], bfr[4];
      #pragma unroll
      for (int m=0;m<8;m++){
        int r_ = wr*128 + m*16 + lr;
        af[m] = *(const bf16x8*)(bA + r_*128 + ((ks*64 + g*16) ^ ((r_&7)<<4)));
      }
      #pragma unroll
      for (int n=0;n<4;n++){
        int r_ = wc*64 + n*16 + lr;
        bfr[n] = *(const bf16x8*)(bB + r_*128 + ((ks*64 + g*16) ^ ((r_&7)<<4)));
      }
      __builtin_amdgcn_s_setprio(1);
      #pragma unroll
      for (int m=0;m<8;m++)
        #pragma unroll
        for (int n=0;n<4;n++)
          acc[m][n] = __builtin_amdgcn_mfma_f32_16x16x32_bf16(af[m], bfr[n], acc[m][n], 0,0,0);
      __builtin_amdgcn_s_setprio(0);
    }
    __builtin_amdgcn_s_barrier();
    if (t+2 < NT){
      STAGE_G1(smem + (t&1)*65536, (t+2)*64);
      asm volatile("s_waitcnt vmcnt(8)" ::: "memory");
      __builtin_amdgcn_s_barrier();
    } else if (t+1 < NT){
      asm volatile("s_waitcnt vmcnt(0)" ::: "memory");
      __builtin_amdgcn_s_barrier();
    }
  }
#undef STAGE_G1

  // free-running fused epilogue: ping-pong per-wave ep buffers (8 KB/wave,
  // in buf0 region; final K-tile was buf1 -> disjoint) + S prefetch.
  float* ep0 = (float*)(smem + (w << 13));
  float* ep1 = ep0 + 1024;
  const float* Sb = S + (long)b*TD_*TE_;
  float* NSb = NS + (long)b*TD_*TE_;
  short* attb = att + (long)b*TD_*TE_;
  int elc = (lane & 15) * 4;

  // write m=0 transpose
  #pragma unroll
  for (int n=0;n<4;n++)
    #pragma unroll
    for (int r=0;r<4;r++){
      int tr = g*4 + r;
      ep0[tr*64 + ((n*16 + lr) ^ (tr << 2))] = acc[0][n][r];
    }

  f32x4 svp[4];
  #pragma unroll
  for (int j=0;j<4;j++){
    int tr = j*4 + (lane >> 4);
    long off = (long)(t0 + wr*128 + tr)*TE_ + e0 + wc*64 + elc;
    svp[j] = *(const f32x4*)(Sb + off);
  }

  #pragma unroll
  for (int m=0;m<8;m++){
    float* cur = (m & 1) ? ep1 : ep0;
    float* nxt = (m & 1) ? ep0 : ep1;
    WAVE_FENCE();                         // write(m) visible for own-wave reads
    f32x4 c4[4];
    #pragma unroll
    for (int j=0;j<4;j++){
      int tr = j*4 + (lane >> 4);
      c4[j] = *(const f32x4*)(cur + tr*64 + (elc ^ (tr << 2)));
    }
    if (m < 7){                           // write m+1 into other buffer now;
      #pragma unroll                      // completes under compute(m)
      for (int n=0;n<4;n++)
        #pragma unroll
        for (int r=0;r<4;r++){
          int tr = g*4 + r;
          nxt[tr*64 + ((n*16 + lr) ^ (tr << 2))] = acc[m+1][n][r];
        }
    }
    f32x4 svn[4];
    if (m < 7){
      #pragma unroll
      for (int j=0;j<4;j++){
        int tr = j*4 + (lane >> 4);
        long off = (long)(t0 + wr*128 + (m+1)*16 + tr)*TE_ + e0 + wc*64 + elc;
        svn[j] = *(const f32x4*)(Sb + off);
      }
    }
    #pragma unroll
    for (int j=0;j<4;j++){
      int tr = j*4 + (lane >> 4);
      int tl = wr*128 + m*16 + tr;
      long off = (long)(t0 + tl)*TE_ + e0 + wc*64 + elc;
      f32x4 sv = svp[j];
      f32x4 ns; bf16x4 ab; float rp = 0.f;
      #pragma unroll
      for (int i=0;i<4;i++){
        float ta = __expf(c4[j][i]);
        ns[i] = ta + sv[i];
        float av = ta * __builtin_amdgcn_rcpf(sv[i]);
        ab[i] = f2b(av);
        rp += av;
      }
      *(f32x4*)(NSb + off) = ns;
      *(bf16x4*)(attb + off) = ab;
      rp += __shfl_xor(rp, 1);
      rp += __shfl_xor(rp, 2);
      rp += __shfl_xor(rp, 4);
      rp += __shfl_xor(rp, 8);
      if (lr == 0) rsLds[wc][tl] = rp;   // single writer per (wc,row)
    }
    if (m < 7){
      #pragma unroll
      for (int j=0;j<4;j++) svp[j] = svn[j];
    }
  }

  __syncthreads();                        // publish rsLds across waves
  if (tid < 256){
    float v = rsLds[0][tid] + rsLds[1][tid] + rsLds[2][tid] + rsLds[3][tid];
    rsp[((long)b*8 + bx)*TD_ + t0 + tid] = v;
  }
}

// ---- k_ctx: r13-exact 128x128 BK=64 4-wave pipelined GEMM ----
#define STAGE12(dstbase, Asrc, Bsrc, ld, kk)                                 \
  { char* _dA = (dstbase); char* _dB = (dstbase) + 16384;                    \
    _Pragma("unroll")                                                        \
    for (int p=0;p<4;p++){                                                   \
      int cb = (w*4+p)*64; int c = cb + lane;                                \
      int row = c >> 3; int cs = (c & 7) ^ (row & 7);                        \
      gload16((Asrc) + (long)row*(ld) + (kk) + cs*8, _dA + cb*16);           \
      gload16((Bsrc) + (long)row*(ld) + (kk) + cs*8, _dB + cb*16);           \
    } }

#define FRAGS12(bA, bB)                                                      \
    _Pragma("unroll")                                                        \
    for (int ks=0;ks<2;ks++){                                                \
      bf16x8 af[4], bfr[4];                                                  \
      _Pragma("unroll")                                                      \
      for (int m=0;m<4;m++){                                                 \
        int r_ = wr*64 + m*16 + lr;                                          \
        af[m] = *(const bf16x8*)((bA) + r_*128 + ((ks*64 + g*16) ^ ((r_&7)<<4))); \
      }                                                                      \
      _Pragma("unroll")                                                      \
      for (int n=0;n<4;n++){                                                 \
        int r_ = wc*64 + n*16 + lr;                                          \
        bfr[n] = *(const bf16x8*)((bB) + r_*128 + ((ks*64 + g*16) ^ ((r_&7)<<4))); \
      }                                                                      \
      __builtin_amdgcn_s_setprio(1);                                         \
      _Pragma("unroll")                                                      \
      for (int m=0;m<4;m++)                                                  \
        _Pragma("unroll")                                                    \
        for (int n=0;n<4;n++)                                                \
          acc[m][n] = __builtin_amdgcn_mfma_f32_16x16x32_bf16(af[m], bfr[n], acc[m][n], 0,0,0); \
      __builtin_amdgcn_s_setprio(0);                                         \
    }

__global__ __launch_bounds__(256,1) void k_ctx(
    const short* __restrict__ att, const short* __restrict__ Ebf,
    const float* __restrict__ rsp, float* __restrict__ ctx){
  __shared__ __align__(16) char smem[65536];
  __shared__ float invRs[128];
  int wg = blockIdx.x + 4*(blockIdx.y + 4*blockIdx.z);
  int lin = (wg & 7)*64 + (wg >> 3);
  int bx = lin & 3, byy = (lin >> 2) & 3, b = lin >> 4;
  int t0 = byy << 7, h0 = bx << 7;

  int tid = threadIdx.x, lane = tid & 63, w = tid >> 6;
  int wr = w >> 1, wc = w & 1, g = lane >> 4, lr = lane & 15;

  if (tid < 128){
    float s = 0.f;
    #pragma unroll
    for (int k=0;k<8;k++) s += rsp[((long)b*8 + k)*TD_ + t0 + tid];
    invRs[tid] = __builtin_amdgcn_rcpf(s);
  }

  const short* Ag = att + (long)b*TD_*TE_ + (long)t0*TE_;
  const short* Bg = Ebf + (long)b*H_*TE_ + (long)h0*TE_;

  const f32x4 fz = {0.f,0.f,0.f,0.f};
  f32x4 acc[4][4];
  #pragma unroll
  for (int m=0;m<4;m++)
    #pragma unroll
    for (int n=0;n<4;n++) acc[m][n] = fz;

  const int NT = TE_/64;     // 32
  STAGE12(smem,       Ag, Bg, TE_, 0);
  STAGE12(smem+32768, Ag, Bg, TE_, 64);
  asm volatile("s_waitcnt vmcnt(8)" ::: "memory");
  __builtin_amdgcn_s_barrier();

  for (int t=0; t<NT; ++t){
    char* bA = smem + (t&1)*32768;
    char* bB = bA + 16384;
    FRAGS12(bA, bB);
    __builtin_amdgcn_s_barrier();
    if (t+2 < NT){
      STAGE12(smem + (t&1)*32768, Ag, Bg, TE_, (t+2)*64);
      asm volatile("s_waitcnt vmcnt(8)" ::: "memory");
      __builtin_amdgcn_s_barrier();
    } else if (t+1 < NT){
      asm volatile("s_waitcnt vmcnt(0)" ::: "memory");
      __builtin_amdgcn_s_barrier();
    }
  }

  // free-running epilogue: per-wave private transpose + wave-local fences
  float* ep = (float*)(smem + (w << 12));
  int hlc = (lane & 15) * 4;
  #pragma unroll
  for (int m=0;m<4;m++){
    #pragma unroll
    for (int n=0;n<4;n++){
      #pragma unroll
      for (int r=0;r<4;r++){
        int tr = g*4 + r;
        ep[tr*64 + ((n*16 + lr) ^ (tr << 2))] = acc[m][n][r];
      }
    }
    WAVE_FENCE();
    #pragma unroll
    for (int j=0;j<4;j++){
      int tr = j*4 + (lane >> 4);
      f32x4 c4 = *(const f32x4*)(ep + tr*64 + (hlc ^ (tr << 2)));
      int tl = wr*64 + m*16 + tr;
      float inv = invRs[tl];
      c4[0]*=inv; c4[1]*=inv; c4[2]*=inv; c4[3]*=inv;
      *(f32x4*)(ctx + (long)(t0 + tl)*B_*H_ + (long)b*H_ + h0 + wc*64 + hlc) = c4;
    }
    WAVE_FENCE();
  }
}

extern "C" void kernel_launch(void* const* d_in, const int* in_sizes, int n_in,
                              void* d_out, int out_size, void* d_ws, size_t ws_size,
                              hipStream_t stream){
  const float* oh = (const float*)d_in[0];   // (TD,B,H)
  const float* E  = (const float*)d_in[1];   // (B,H,TE)
  const float* S  = (const float*)d_in[2];   // (B,TD,TE)
  float* out_ctx = (float*)d_out;                       // (TD,B,H)
  float* out_ns  = out_ctx + (long)TD_*B_*H_;           // (B,TD,TE)

  char* ws = (char*)d_ws;
  size_t offEbt = 0;
  size_t offEbf = offEbt + (size_t)B_*TE_*H_*2;   // 64 MiB
  size_t offA   = offEbf + (size_t)B_*H_*TE_*2;   // 64 MiB
  size_t offAt  = offA   + (size_t)B_*TD_*H_*2;   // 16 MiB
  size_t offRsp = offAt  + (size_t)B_*TD_*TE_*2;  // 64 MiB (att bf16)
  short* Ebt  = (short*)(ws + offEbt);
  short* Ebf  = (short*)(ws + offEbf);
  short* Abf  = (short*)(ws + offA);
  short* attw = (short*)(ws + offAt);
  float* rsp  = (float*)(ws + offRsp);            // [B][8][TD] partials: 512 KiB

  k_prep_all<<<dim3(32, 16, 32), 256, 0, stream>>>(E, Ebf, Ebt, oh, Abf);
  k_gemm1<<<dim3(TE_/256, TD_/256, B_), 512, 0, stream>>>(Abf, Ebt, S, out_ns, attw, rsp);
  k_ctx<<<dim3(H_/128, TD_/128, B_), 256, 0, stream>>>(attw, Ebf, rsp, out_ctx);
}